// Round 6
// baseline (133.861 us; speedup 1.0000x reference)
//
#include <hip/hip_runtime.h>

// NCF fused forward, v6: wave-autonomous (ZERO barriers in main).
//  ncf_prep : blocks 0..B-1 (128 thr): Xu[b] = b1 + (eu_m+bu_m)@W1u + bi_mlp@W1i (f32),
//             wup[b] = (eu_g+bu_g).*Wp[0:64], cu[b] = wup[b].bi_gmf
//             blocks B.. : W1iT/W2T/W3T transposes to bf16 [out][in]
//  ncf_main : each WAVE independently processes 16-pair micro-tiles:
//             A1 loaded straight from global (fp32->bf16 in reg),
//             GEMM1 K=64 (+Xu), h1 -> wave-private LDS,
//             GEMM2 K=128, h2 -> wave-private LDS, GEMM3 K=64,
//             gmf dot + final dot + sigmoid all in-register.

typedef __attribute__((ext_vector_type(8))) short bf16x8;
typedef __attribute__((ext_vector_type(4))) float f32x4;

union pk8 { int4 i; bf16x8 v; };

__device__ __forceinline__ short f2bf(float x){
  unsigned u = __float_as_uint(x);
  u += 0x7fffu + ((u >> 16) & 1u);
  return (short)(u >> 16);
}
__device__ __forceinline__ unsigned pk2(float lo, float hi){
  return (__float_as_uint(hi) & 0xFFFF0000u) | (__float_as_uint(lo) >> 16);
}
__device__ __forceinline__ bf16x8 pack8(float4 a, float4 b){
  pk8 u;
  u.i.x = pk2(a.x, a.y); u.i.y = pk2(a.z, a.w);
  u.i.z = pk2(b.x, b.y); u.i.w = pk2(b.z, b.w);
  return u.v;
}
__device__ __forceinline__ short tbf(float x){       // truncate
  return (short)(__float_as_uint(x) >> 16);
}

// ws layout (bytes):
//   0      W1iT bf16 [128][64]   (16384)
//   16384  W2T  bf16 [64][128]   (16384)
//   32768  W3T  bf16 [32][64]    (4096)
//   36864  Xu   f32  [B][128]
//   then   wup  f32  [B][64],  cu f32 [B]

__global__ __launch_bounds__(128) void ncf_prep(
    const int* __restrict__ user,
    const float* __restrict__ Wu_gmf, const float* __restrict__ bu_gmf,
    const float* __restrict__ Wu_mlp, const float* __restrict__ bu_mlp,
    const float* __restrict__ bi_gmf, const float* __restrict__ bi_mlp,
    const float* __restrict__ W1, const float* __restrict__ b1,
    const float* __restrict__ W2, const float* __restrict__ W3,
    const float* __restrict__ Wp,
    short* __restrict__ wsT, float* __restrict__ Xu,
    float* __restrict__ wup, float* __restrict__ cu, int B)
{
  int bid = blockIdx.x;
  int j = threadIdx.x;
  if (bid < B){
    long u = (long)user[bid];
    float acc = b1[j];
    #pragma unroll 4
    for (int k = 0; k < 64; k++){
      float eu = Wu_mlp[u*64 + k] + bu_mlp[k];
      acc += eu * W1[k*128 + j] + bi_mlp[k] * W1[(64 + k)*128 + j];
    }
    Xu[(long)bid*128 + j] = acc;
    if (j < 64){
      float wg = (Wu_gmf[u*64 + j] + bu_gmf[j]) * Wp[j];
      wup[(long)bid*64 + j] = wg;
      float c = wg * bi_gmf[j];
      c += __shfl_xor(c, 1);  c += __shfl_xor(c, 2);
      c += __shfl_xor(c, 4);  c += __shfl_xor(c, 8);
      c += __shfl_xor(c, 16); c += __shfl_xor(c, 32);
      if (j == 0) cu[bid] = c;
    }
    return;
  }
  int i = (bid - B)*128 + j;                    // 0..18431
  if (i < 8192){                                // W1iT[col][k] = W1[64+k][col]
    int col = i >> 6, k = i & 63;
    wsT[i] = f2bf(W1[(64 + k)*128 + col]);
  } else if (i < 16384){                        // W2T[col][k] = W2[k][col]
    int t = i - 8192; int col = t >> 7, k = t & 127;
    wsT[i] = f2bf(W2[k*64 + col]);
  } else if (i < 18432){                        // W3T[col][k] = W3[k][col]
    int t = i - 16384; int col = t >> 6, k = t & 63;
    wsT[i] = f2bf(W3[k*32 + col]);
  }
}

#define H1LD 130   // shorts per h1 row (65 words, odd -> banks spread)
#define H2LD 66    // shorts per h2 row (33 words, odd)

__global__ __launch_bounds__(256) void ncf_main(
    const int* __restrict__ item,
    const float* __restrict__ Wi_mlp, const float* __restrict__ Wi_gmf,
    const short* __restrict__ W1iT, const short* __restrict__ W2T,
    const short* __restrict__ W3T,
    const float* __restrict__ b2, const float* __restrict__ b3,
    const float* __restrict__ Wp, const float* __restrict__ bp,
    const float* __restrict__ Xu, const float* __restrict__ wup,
    const float* __restrict__ cu,
    float* __restrict__ out, int N, int total, int nmt)
{
  __shared__ __align__(16) short s_h1[4][16*H1LD];
  __shared__ __align__(16) short s_h2[4][16*H2LD];

  const int tid = threadIdx.x;
  const int w   = tid >> 6, l = tid & 63;
  const int c   = l & 15,  seg = l >> 4;
  short* h1 = &s_h1[w][0];
  short* h2 = &s_h2[w][0];

  // GEMM3 weights hoisted (4 frags = 16 VGPR)
  bf16x8 w3f[2][2];
  #pragma unroll
  for (int nt = 0; nt < 2; nt++)
    #pragma unroll
    for (int ks = 0; ks < 2; ks++)
      w3f[nt][ks] = *(const bf16x8*)&W3T[(nt*16 + c)*64 + ks*32 + seg*8];

  const float bp0 = bp[0];
  float wp3[2], b3r[2], b2r[4];
  #pragma unroll
  for (int nt = 0; nt < 2; nt++){ wp3[nt] = Wp[64 + nt*16 + c]; b3r[nt] = b3[nt*16 + c]; }
  #pragma unroll
  for (int nt = 0; nt < 4; nt++) b2r[nt] = b2[nt*16 + c];

  const int gw = blockIdx.x*4 + w;      // global wave id
  const int nw = gridDim.x*4;

  for (int mt = gw; mt < nmt; mt += nw){
    const int p0  = mt * 16;
    const int b0  = p0 / N;
    const int thr = (b0 + 1) * N;

    // ---- my A-row (row = c) : item index, mlp row (->bf16 frags), gmf row ----
    int pA = p0 + c; if (pA >= total) pA = total - 1;
    const long ib = (long)item[pA] * 64;
    const int  bA = b0 + ((pA >= thr) ? 1 : 0);

    bf16x8 a1[2];
    #pragma unroll
    for (int ks = 0; ks < 2; ks++){
      const float4* ap = (const float4*)(Wi_mlp + ib + ks*32 + seg*8);
      float4 x = ap[0], y = ap[1];
      a1[ks] = pack8(x, y);
    }

    // gmf partial dot: pg = wup[bA] . Wi_gmf_row (my 16 elems), reduce over segs
    float pg;
    {
      const float4* gp = (const float4*)(Wi_gmf + ib + seg*16);
      const float4* wq = (const float4*)(wup + (long)bA*64 + seg*16);
      float s = 0.f;
      #pragma unroll
      for (int jj = 0; jj < 4; jj++){
        float4 g = gp[jj], v = wq[jj];
        s += g.x*v.x + g.y*v.y + g.z*v.z + g.w*v.w;
      }
      s += __shfl_xor(s, 16);
      s += __shfl_xor(s, 32);
      pg = s + cu[bA];
    }

    // Xu bias rows (<=2 distinct users per 16-pair tile)
    float xu0[8], xu1[8];
    #pragma unroll
    for (int nt = 0; nt < 8; nt++) xu0[nt] = Xu[(long)b0*128 + nt*16 + c];
    const bool span = (thr < p0 + 16);
    if (span){
      #pragma unroll
      for (int nt = 0; nt < 8; nt++) xu1[nt] = Xu[(long)(b0+1)*128 + nt*16 + c];
    } else {
      #pragma unroll
      for (int nt = 0; nt < 8; nt++) xu1[nt] = xu0[nt];
    }

    // ---- GEMM1: h1[16x128] = relu(item @ W1i + Xu), K=64 ----
    f32x4 acc1[8];
    #pragma unroll
    for (int nt = 0; nt < 8; nt++) acc1[nt] = (f32x4){0.f,0.f,0.f,0.f};
    #pragma unroll
    for (int ks = 0; ks < 2; ks++)
      #pragma unroll
      for (int nt = 0; nt < 8; nt++){
        bf16x8 bfg = *(const bf16x8*)&W1iT[(nt*16 + c)*64 + ks*32 + seg*8];
        acc1[nt] = __builtin_amdgcn_mfma_f32_16x16x32_bf16(a1[ks], bfg, acc1[nt], 0, 0, 0);
      }
    #pragma unroll
    for (int nt = 0; nt < 8; nt++)
      #pragma unroll
      for (int rr = 0; rr < 4; rr++){
        int row = seg*4 + rr;
        float xv = (p0 + row >= thr) ? xu1[nt] : xu0[nt];
        float v = acc1[nt][rr] + xv;
        v = v > 0.f ? v : 0.f;
        h1[row*H1LD + nt*16 + c] = tbf(v);
      }

    // ---- GEMM2: h2[16x64] = relu(h1 @ W2 + b2), K=128 ----
    f32x4 acc2[4];
    #pragma unroll
    for (int nt = 0; nt < 4; nt++) acc2[nt] = (f32x4){0.f,0.f,0.f,0.f};
    #pragma unroll
    for (int ks = 0; ks < 4; ks++){
      bf16x8 a = *(const bf16x8*)&h1[c*H1LD + ks*32 + seg*8];
      #pragma unroll
      for (int nt = 0; nt < 4; nt++){
        bf16x8 bfg = *(const bf16x8*)&W2T[(nt*16 + c)*128 + ks*32 + seg*8];
        acc2[nt] = __builtin_amdgcn_mfma_f32_16x16x32_bf16(a, bfg, acc2[nt], 0, 0, 0);
      }
    }
    #pragma unroll
    for (int nt = 0; nt < 4; nt++)
      #pragma unroll
      for (int rr = 0; rr < 4; rr++){
        int row = seg*4 + rr;
        float v = acc2[nt][rr] + b2r[nt];
        v = v > 0.f ? v : 0.f;
        h2[row*H2LD + nt*16 + c] = tbf(v);
      }

    // ---- GEMM3: h3[16x32] = relu(h2 @ W3 + b3), K=64 ----
    f32x4 acc3[2];
    #pragma unroll
    for (int nt = 0; nt < 2; nt++) acc3[nt] = (f32x4){0.f,0.f,0.f,0.f};
    #pragma unroll
    for (int ks = 0; ks < 2; ks++){
      bf16x8 a = *(const bf16x8*)&h2[c*H2LD + ks*32 + seg*8];
      #pragma unroll
      for (int nt = 0; nt < 2; nt++)
        acc3[nt] = __builtin_amdgcn_mfma_f32_16x16x32_bf16(a, w3f[nt][ks], acc3[nt], 0, 0, 0);
    }

    // ---- final: per-row dot over 32 h3 cols, + pg, sigmoid ----
    float t0 = 0.f, t1 = 0.f, t2 = 0.f, t3 = 0.f;
    #pragma unroll
    for (int nt = 0; nt < 2; nt++){
      float v0 = acc3[nt][0] + b3r[nt]; v0 = v0 > 0.f ? v0 : 0.f;
      float v1 = acc3[nt][1] + b3r[nt]; v1 = v1 > 0.f ? v1 : 0.f;
      float v2 = acc3[nt][2] + b3r[nt]; v2 = v2 > 0.f ? v2 : 0.f;
      float v3 = acc3[nt][3] + b3r[nt]; v3 = v3 > 0.f ? v3 : 0.f;
      t0 += v0 * wp3[nt]; t1 += v1 * wp3[nt];
      t2 += v2 * wp3[nt]; t3 += v3 * wp3[nt];
    }
    #pragma unroll
    for (int m = 1; m < 16; m <<= 1){
      t0 += __shfl_xor(t0, m);
      t1 += __shfl_xor(t1, m);
      t2 += __shfl_xor(t2, m);
      t3 += __shfl_xor(t3, m);
    }
    if (c < 4){
      int row = seg*4 + c;
      float tv = (c == 0) ? t0 : (c == 1) ? t1 : (c == 2) ? t2 : t3;
      float pgr = __shfl(pg, row);     // lane 'row' holds pg for row (l&15==row)
      int p = p0 + row;
      if (p < total){
        float z = tv + pgr + bp0;
        out[p] = 1.f / (1.f + __expf(-z));
      }
    }
  }
}

extern "C" void kernel_launch(void* const* d_in, const int* in_sizes, int n_in,
                              void* d_out, int out_size, void* d_ws, size_t ws_size,
                              hipStream_t stream)
{
  const int*   user   = (const int*)  d_in[0];
  const int*   item   = (const int*)  d_in[1];
  const float* Wu_gmf = (const float*)d_in[3];
  const float* bu_gmf = (const float*)d_in[4];
  const float* Wu_mlp = (const float*)d_in[5];
  const float* bu_mlp = (const float*)d_in[6];
  const float* Wi_gmf = (const float*)d_in[7];
  const float* bi_gmf = (const float*)d_in[8];
  const float* Wi_mlp = (const float*)d_in[9];
  const float* bi_mlp = (const float*)d_in[10];
  const float* W1     = (const float*)d_in[11];
  const float* b1     = (const float*)d_in[12];
  const float* W2     = (const float*)d_in[13];
  const float* b2     = (const float*)d_in[14];
  const float* W3     = (const float*)d_in[15];
  const float* b3     = (const float*)d_in[16];
  const float* Wp     = (const float*)d_in[17];
  const float* bp     = (const float*)d_in[18];

  int B     = in_sizes[0];            // 4096
  int total = in_sizes[1];            // 409600
  int N     = total / B;              // 100

  char* wsb = (char*)d_ws;
  short* W1iT = (short*)wsb;                     // [128][64]
  short* W2T  = (short*)(wsb + 16384);           // [64][128]
  short* W3T  = (short*)(wsb + 32768);           // [32][64]
  float* Xu   = (float*)(wsb + 36864);           // B*128
  float* wup  = Xu  + (size_t)B * 128;           // B*64
  float* cuv  = wup + (size_t)B * 64;            // B

  ncf_prep<<<B + 144, 128, 0, stream>>>(user, Wu_gmf, bu_gmf, Wu_mlp, bu_mlp,
                                        bi_gmf, bi_mlp, W1, b1, W2, W3, Wp,
                                        (short*)d_ws, Xu, wup, cuv, B);

  int nmt = (total + 15) / 16;        // 25600 micro-tiles
  ncf_main<<<2048, 256, 0, stream>>>(item, Wi_mlp, Wi_gmf,
      W1iT, W2T, W3T, b2, b3, Wp, bp, Xu, wup, cuv,
      (float*)d_out, N, total, nmt);
}

// Round 7
// 108.400 us; speedup vs baseline: 1.2349x; 1.2349x over previous
//
#include <hip/hip_runtime.h>

// NCF fused forward, v7: two-pass (gather/stage + dense compute).
//  ncf_prep   : blocks 0..B-1: Xu[b]=b1+(eu_m+bu_m)@W1u+bi_mlp@W1i; wup[b]=(eu_g+bu_g).*Wp[0:64];
//               cu[b]=wup[b].bi_gmf.  blocks B..: W1iT/W2T/W3T -> bf16 [out][in].
//  ncf_gather : pure gather. 4 lanes/pair: item mlp row -> bf16 inter[p][64];
//               pg[p] = wup[b].(Wi_gmf row) + cu[b].
//  ncf_dense  : r3 block structure, staged coalesced loads instead of gather.
//  (fallback  : fused r3-style main if ws too small for staging)

typedef __attribute__((ext_vector_type(8))) short bf16x8;
typedef __attribute__((ext_vector_type(4))) float f32x4;

__device__ __forceinline__ short f2bf(float x){
  unsigned u = __float_as_uint(x);
  u += 0x7fffu + ((u >> 16) & 1u);
  return (short)(u >> 16);
}
__device__ __forceinline__ float bf2f(short s){
  return __uint_as_float(((unsigned)(unsigned short)s) << 16);
}

// ---------------- prep ----------------
__global__ __launch_bounds__(128) void ncf_prep(
    const int* __restrict__ user,
    const float* __restrict__ Wu_gmf, const float* __restrict__ bu_gmf,
    const float* __restrict__ Wu_mlp, const float* __restrict__ bu_mlp,
    const float* __restrict__ bi_gmf, const float* __restrict__ bi_mlp,
    const float* __restrict__ W1, const float* __restrict__ b1,
    const float* __restrict__ W2, const float* __restrict__ W3,
    const float* __restrict__ Wp,
    short* __restrict__ wsT, float* __restrict__ Xu,
    float* __restrict__ wup, float* __restrict__ cu, int B)
{
  int bid = blockIdx.x;
  int j = threadIdx.x;
  if (bid < B){
    long u = (long)user[bid];
    float acc = b1[j];
    #pragma unroll 4
    for (int k = 0; k < 64; k++){
      float eu = Wu_mlp[u*64 + k] + bu_mlp[k];
      acc += eu * W1[k*128 + j] + bi_mlp[k] * W1[(64 + k)*128 + j];
    }
    Xu[(long)bid*128 + j] = acc;
    if (j < 64){
      float wg = (Wu_gmf[u*64 + j] + bu_gmf[j]) * Wp[j];
      wup[(long)bid*64 + j] = wg;
      float c = wg * bi_gmf[j];
      c += __shfl_xor(c, 1);  c += __shfl_xor(c, 2);
      c += __shfl_xor(c, 4);  c += __shfl_xor(c, 8);
      c += __shfl_xor(c, 16); c += __shfl_xor(c, 32);
      if (j == 0) cu[bid] = c;
    }
    return;
  }
  int i = (bid - B)*128 + j;                    // 0..18431
  if (i < 8192){                                // W1iT[col][k] = W1[64+k][col]
    int col = i >> 6, k = i & 63;
    wsT[i] = f2bf(W1[(64 + k)*128 + col]);
  } else if (i < 16384){                        // W2T[col][k] = W2[k][col]
    int t = i - 8192; int col = t >> 7, k = t & 127;
    wsT[i] = f2bf(W2[k*64 + col]);
  } else if (i < 18432){                        // W3T[col][k] = W3[k][col]
    int t = i - 16384; int col = t >> 6, k = t & 63;
    wsT[i] = f2bf(W3[k*32 + col]);
  }
}

// ---------------- pass A: pure gather/stage ----------------
__global__ __launch_bounds__(256) void ncf_gather(
    const int* __restrict__ item,
    const float* __restrict__ Wi_mlp, const float* __restrict__ Wi_gmf,
    const float* __restrict__ wup, const float* __restrict__ cu,
    short* __restrict__ interg, float* __restrict__ pgg,
    int N, int total)
{
  const int q = threadIdx.x & 3;
  int g = (blockIdx.x*256 + threadIdx.x) >> 2;
  const int gs = (gridDim.x*256) >> 2;
  for (int p = g; p < total; p += gs){
    int b = p / N;
    long ib = (long)item[p] * 64;
    const float4* mp = (const float4*)(Wi_mlp + ib) + q*4;
    const float4* gp = (const float4*)(Wi_gmf + ib) + q*4;
    const float4* wq = (const float4*)(wup + (long)b*64) + q*4;
    bf16x8 o0, o1;
    float pg = 0.f;
    #pragma unroll
    for (int j = 0; j < 4; j++){
      float4 m = mp[j];
      float4 gv = gp[j];
      float4 wv = wq[j];
      pg += gv.x*wv.x + gv.y*wv.y + gv.z*wv.z + gv.w*wv.w;
      bf16x8& o = (j < 2) ? o0 : o1;
      int s = (j & 1) * 4;
      o[s+0] = f2bf(m.x); o[s+1] = f2bf(m.y);
      o[s+2] = f2bf(m.z); o[s+3] = f2bf(m.w);
    }
    short* dst = interg + (long)p*64 + q*16;
    *(bf16x8*)dst       = o0;
    *(bf16x8*)(dst + 8) = o1;
    pg += __shfl_xor(pg, 1);
    pg += __shfl_xor(pg, 2);
    if (q == 0) pgg[p] = pg + cu[b];
  }
}

// ---------------- pass B: dense compute ----------------
__global__ __launch_bounds__(256) void ncf_dense(
    const short* __restrict__ interg, const float* __restrict__ pgg,
    const short* __restrict__ W1iT, const short* __restrict__ W2T,
    const short* __restrict__ W3T,
    const float* __restrict__ b2, const float* __restrict__ b3,
    const float* __restrict__ Wp, const float* __restrict__ bp,
    const float* __restrict__ Xu,
    float* __restrict__ out, int N, int total, int Bsz)
{
  __shared__ __align__(16) short s_item[64][72];   // staged rows; reused as h2
  __shared__ __align__(16) short s_h1[64][136];
  __shared__ __align__(16) short s_h3[64][34];
  __shared__ __align__(16) float s_xu[2][128];
  __shared__           float s_pg[64];

  const int tid = threadIdx.x;
  const int p0  = blockIdx.x * 64;
  const int b0  = p0 / N;
  const int thr = (b0 + 1) * N;
  const int r   = tid >> 2, q = tid & 3;

  // ---- load staged rows (coalesced, L3-hot) + pg + Xu ----
  {
    const short* src = interg + (long)(p0 + r)*64 + q*16;
    *(bf16x8*)&s_item[r][q*16]     = *(const bf16x8*)src;
    *(bf16x8*)&s_item[r][q*16 + 8] = *(const bf16x8*)(src + 8);
    if (q == 0) s_pg[r] = pgg[p0 + r];
    int i2 = tid >> 7, col = tid & 127;
    int bb = b0 + i2; if (bb >= Bsz) bb = Bsz - 1;
    s_xu[i2][col] = Xu[(long)bb*128 + col];
  }
  __syncthreads();

  const int w  = tid >> 6, l = tid & 63;
  const int lr = l & 15,  lg = l >> 4;

  // ---- GEMM1: h1 = relu(item @ W1i + Xu[b]), K=64 ----
  {
    f32x4 acc[4][2];
    #pragma unroll
    for (int mt = 0; mt < 4; mt++)
      #pragma unroll
      for (int nt = 0; nt < 2; nt++)
        acc[mt][nt] = (f32x4){0.f, 0.f, 0.f, 0.f};
    #pragma unroll
    for (int ks = 0; ks < 2; ks++){
      bf16x8 af[4];
      #pragma unroll
      for (int mt = 0; mt < 4; mt++)
        af[mt] = *(const bf16x8*)&s_item[mt*16 + lr][ks*32 + lg*8];
      #pragma unroll
      for (int nt = 0; nt < 2; nt++){
        bf16x8 bfg = *(const bf16x8*)&W1iT[(w*32 + nt*16 + lr)*64 + ks*32 + lg*8];
        #pragma unroll
        for (int mt = 0; mt < 4; mt++)
          acc[mt][nt] = __builtin_amdgcn_mfma_f32_16x16x32_bf16(af[mt], bfg, acc[mt][nt], 0, 0, 0);
      }
    }
    #pragma unroll
    for (int nt = 0; nt < 2; nt++){
      int col = w*32 + nt*16 + lr;
      #pragma unroll
      for (int mt = 0; mt < 4; mt++)
        #pragma unroll
        for (int rr = 0; rr < 4; rr++){
          int row = mt*16 + lg*4 + rr;
          int bl = (p0 + row >= thr) ? 1 : 0;
          float v = acc[mt][nt][rr] + s_xu[bl][col];
          s_h1[row][col] = f2bf(v > 0.f ? v : 0.f);
        }
    }
  }
  __syncthreads();

  // ---- GEMM2: h2 = relu(h1 @ W2 + b2) -> s_item cols 0..63 ----
  {
    f32x4 acc2[4];
    #pragma unroll
    for (int mt = 0; mt < 4; mt++) acc2[mt] = (f32x4){0.f, 0.f, 0.f, 0.f};
    #pragma unroll
    for (int ks = 0; ks < 4; ks++){
      bf16x8 bfg = *(const bf16x8*)&W2T[(w*16 + lr)*128 + ks*32 + lg*8];
      #pragma unroll
      for (int mt = 0; mt < 4; mt++){
        bf16x8 a = *(const bf16x8*)&s_h1[mt*16 + lr][ks*32 + lg*8];
        acc2[mt] = __builtin_amdgcn_mfma_f32_16x16x32_bf16(a, bfg, acc2[mt], 0, 0, 0);
      }
    }
    int col = w*16 + lr;
    float bb = b2[col];
    #pragma unroll
    for (int mt = 0; mt < 4; mt++)
      #pragma unroll
      for (int rr = 0; rr < 4; rr++){
        int row = mt*16 + lg*4 + rr;
        float v = acc2[mt][rr] + bb;
        s_item[row][col] = f2bf(v > 0.f ? v : 0.f);
      }
  }
  __syncthreads();

  // ---- GEMM3: h3 = relu(h2 @ W3 + b3), waves 0,1 ----
  if (w < 2){
    f32x4 acc3[4];
    #pragma unroll
    for (int mt = 0; mt < 4; mt++) acc3[mt] = (f32x4){0.f, 0.f, 0.f, 0.f};
    #pragma unroll
    for (int ks = 0; ks < 2; ks++){
      bf16x8 bfg = *(const bf16x8*)&W3T[(w*16 + lr)*64 + ks*32 + lg*8];
      #pragma unroll
      for (int mt = 0; mt < 4; mt++){
        bf16x8 a = *(const bf16x8*)&s_item[mt*16 + lr][ks*32 + lg*8];
        acc3[mt] = __builtin_amdgcn_mfma_f32_16x16x32_bf16(a, bfg, acc3[mt], 0, 0, 0);
      }
    }
    int col = w*16 + lr;
    float bb = b3[col];
    #pragma unroll
    for (int mt = 0; mt < 4; mt++)
      #pragma unroll
      for (int rr = 0; rr < 4; rr++){
        int row = mt*16 + lg*4 + rr;
        float v = acc3[mt][rr] + bb;
        s_h3[row][col] = f2bf(v > 0.f ? v : 0.f);
      }
  }
  __syncthreads();

  // ---- final: out = sigmoid(pg + h3 . Wp[64:96] + bp) ----
  {
    float sum = 0.f;
    #pragma unroll
    for (int i = 0; i < 8; i++){
      int c = q*8 + i;
      sum += bf2f(s_h3[r][c]) * Wp[64 + c];
    }
    sum += __shfl_xor(sum, 1);
    sum += __shfl_xor(sum, 2);
    int p = p0 + r;
    if (q == 0 && p < total){
      float z = s_pg[r] + sum + bp[0];
      out[p] = 1.f / (1.f + __expf(-z));
    }
  }
}

// ---------------- fallback: fused (r3-best) ----------------
__global__ __launch_bounds__(256) void ncf_main_fused(
    const int* __restrict__ item,
    const float* __restrict__ Wi_mlp, const float* __restrict__ Wi_gmf,
    const short* __restrict__ W1iT, const short* __restrict__ W2T,
    const short* __restrict__ W3T,
    const float* __restrict__ b2, const float* __restrict__ b3,
    const float* __restrict__ Wp, const float* __restrict__ bp,
    const float* __restrict__ Xu, const float* __restrict__ wup,
    const float* __restrict__ cu,
    float* __restrict__ out, int N, int total, int Bsz)
{
  __shared__ __align__(16) short s_item[64][72];
  __shared__ __align__(16) short s_h1[64][136];
  __shared__ __align__(16) short s_h3[64][34];
  __shared__ __align__(16) float s_xu[2][128];
  __shared__           float s_pg[64];

  const int tid = threadIdx.x;
  const int p0  = blockIdx.x * 64;
  const int b0  = p0 / N;
  const int thr = (b0 + 1) * N;
  const int r   = tid >> 2, q = tid & 3;
  {
    int p = p0 + r;
    int b = b0 + ((p >= thr) ? 1 : 0);
    long ib = (long)item[p] * 64;
    const float4* imp = (const float4*)(Wi_mlp + ib) + q*4;
    const float4* igp = (const float4*)(Wi_gmf + ib) + q*4;
    const float4* wq  = (const float4*)(wup + (long)b*64) + q*4;
    bf16x8 ia[2];
    float pg = 0.f;
    #pragma unroll
    for (int j = 0; j < 4; j++){
      float4 v = imp[j], gv = igp[j], wv = wq[j];
      pg += gv.x*wv.x + gv.y*wv.y + gv.z*wv.z + gv.w*wv.w;
      int h = j >> 1, s = (j & 1) * 4;
      ia[h][s+0] = f2bf(v.x); ia[h][s+1] = f2bf(v.y);
      ia[h][s+2] = f2bf(v.z); ia[h][s+3] = f2bf(v.w);
    }
    *(bf16x8*)&s_item[r][q*16]     = ia[0];
    *(bf16x8*)&s_item[r][q*16 + 8] = ia[1];
    pg += __shfl_xor(pg, 1);
    pg += __shfl_xor(pg, 2);
    if (q == 0) s_pg[r] = pg + cu[b];
    int i2 = tid >> 7, col = tid & 127;
    int bb = b0 + i2; if (bb >= Bsz) bb = Bsz - 1;
    s_xu[i2][col] = Xu[(long)bb*128 + col];
  }
  __syncthreads();
  const int w  = tid >> 6, l = tid & 63;
  const int lr = l & 15,  lg = l >> 4;
  {
    f32x4 acc[4][2];
    #pragma unroll
    for (int mt = 0; mt < 4; mt++)
      #pragma unroll
      for (int nt = 0; nt < 2; nt++)
        acc[mt][nt] = (f32x4){0.f, 0.f, 0.f, 0.f};
    #pragma unroll
    for (int ks = 0; ks < 2; ks++){
      bf16x8 af[4];
      #pragma unroll
      for (int mt = 0; mt < 4; mt++)
        af[mt] = *(const bf16x8*)&s_item[mt*16 + lr][ks*32 + lg*8];
      #pragma unroll
      for (int nt = 0; nt < 2; nt++){
        bf16x8 bfg = *(const bf16x8*)&W1iT[(w*32 + nt*16 + lr)*64 + ks*32 + lg*8];
        #pragma unroll
        for (int mt = 0; mt < 4; mt++)
          acc[mt][nt] = __builtin_amdgcn_mfma_f32_16x16x32_bf16(af[mt], bfg, acc[mt][nt], 0, 0, 0);
      }
    }
    #pragma unroll
    for (int nt = 0; nt < 2; nt++){
      int col = w*32 + nt*16 + lr;
      #pragma unroll
      for (int mt = 0; mt < 4; mt++)
        #pragma unroll
        for (int rr = 0; rr < 4; rr++){
          int row = mt*16 + lg*4 + rr;
          int bl = (p0 + row >= thr) ? 1 : 0;
          float v = acc[mt][nt][rr] + s_xu[bl][col];
          s_h1[row][col] = f2bf(v > 0.f ? v : 0.f);
        }
    }
  }
  __syncthreads();
  {
    f32x4 acc2[4];
    #pragma unroll
    for (int mt = 0; mt < 4; mt++) acc2[mt] = (f32x4){0.f, 0.f, 0.f, 0.f};
    #pragma unroll
    for (int ks = 0; ks < 4; ks++){
      bf16x8 bfg = *(const bf16x8*)&W2T[(w*16 + lr)*128 + ks*32 + lg*8];
      #pragma unroll
      for (int mt = 0; mt < 4; mt++){
        bf16x8 a = *(const bf16x8*)&s_h1[mt*16 + lr][ks*32 + lg*8];
        acc2[mt] = __builtin_amdgcn_mfma_f32_16x16x32_bf16(a, bfg, acc2[mt], 0, 0, 0);
      }
    }
    int col = w*16 + lr;
    float bb = b2[col];
    #pragma unroll
    for (int mt = 0; mt < 4; mt++)
      #pragma unroll
      for (int rr = 0; rr < 4; rr++){
        int row = mt*16 + lg*4 + rr;
        float v = acc2[mt][rr] + bb;
        s_item[row][col] = f2bf(v > 0.f ? v : 0.f);
      }
  }
  __syncthreads();
  if (w < 2){
    f32x4 acc3[4];
    #pragma unroll
    for (int mt = 0; mt < 4; mt++) acc3[mt] = (f32x4){0.f, 0.f, 0.f, 0.f};
    #pragma unroll
    for (int ks = 0; ks < 2; ks++){
      bf16x8 bfg = *(const bf16x8*)&W3T[(w*16 + lr)*64 + ks*32 + lg*8];
      #pragma unroll
      for (int mt = 0; mt < 4; mt++){
        bf16x8 a = *(const bf16x8*)&s_item[mt*16 + lr][ks*32 + lg*8];
        acc3[mt] = __builtin_amdgcn_mfma_f32_16x16x32_bf16(a, bfg, acc3[mt], 0, 0, 0);
      }
    }
    int col = w*16 + lr;
    float bb = b3[col];
    #pragma unroll
    for (int mt = 0; mt < 4; mt++)
      #pragma unroll
      for (int rr = 0; rr < 4; rr++){
        int row = mt*16 + lg*4 + rr;
        float v = acc3[mt][rr] + bb;
        s_h3[row][col] = f2bf(v > 0.f ? v : 0.f);
      }
  }
  __syncthreads();
  {
    float sum = 0.f;
    #pragma unroll
    for (int i = 0; i < 8; i++){
      int c = q*8 + i;
      sum += bf2f(s_h3[r][c]) * Wp[64 + c];
    }
    sum += __shfl_xor(sum, 1);
    sum += __shfl_xor(sum, 2);
    int p = p0 + r;
    if (q == 0 && p < total){
      float z = s_pg[r] + sum + bp[0];
      out[p] = 1.f / (1.f + __expf(-z));
    }
  }
}

extern "C" void kernel_launch(void* const* d_in, const int* in_sizes, int n_in,
                              void* d_out, int out_size, void* d_ws, size_t ws_size,
                              hipStream_t stream)
{
  const int*   user   = (const int*)  d_in[0];
  const int*   item   = (const int*)  d_in[1];
  const float* Wu_gmf = (const float*)d_in[3];
  const float* bu_gmf = (const float*)d_in[4];
  const float* Wu_mlp = (const float*)d_in[5];
  const float* bu_mlp = (const float*)d_in[6];
  const float* Wi_gmf = (const float*)d_in[7];
  const float* bi_gmf = (const float*)d_in[8];
  const float* Wi_mlp = (const float*)d_in[9];
  const float* bi_mlp = (const float*)d_in[10];
  const float* W1     = (const float*)d_in[11];
  const float* b1     = (const float*)d_in[12];
  const float* W2     = (const float*)d_in[13];
  const float* b2     = (const float*)d_in[14];
  const float* W3     = (const float*)d_in[15];
  const float* b3     = (const float*)d_in[16];
  const float* Wp     = (const float*)d_in[17];
  const float* bp     = (const float*)d_in[18];

  int B     = in_sizes[0];            // 4096
  int total = in_sizes[1];            // 409600
  int N     = total / B;              // 100

  char* wsb = (char*)d_ws;
  short* W1iT = (short*)wsb;                     // [128][64]
  short* W2T  = (short*)(wsb + 16384);           // [64][128]
  short* W3T  = (short*)(wsb + 32768);           // [32][64]
  float* Xu   = (float*)(wsb + 36864);           // B*128 f32
  float* wup  = Xu  + (size_t)B * 128;           // B*64 f32
  float* cuv  = wup + (size_t)B * 64;            // B f32

  size_t base_need = 36864 + (size_t)B*128*4 + (size_t)B*64*4 + (size_t)B*4;
  size_t inter_off = (base_need + 255) & ~(size_t)255;
  size_t need = inter_off + (size_t)total*64*2 + (size_t)total*4;

  ncf_prep<<<B + 144, 128, 0, stream>>>(user, Wu_gmf, bu_gmf, Wu_mlp, bu_mlp,
                                        bi_gmf, bi_mlp, W1, b1, W2, W3, Wp,
                                        (short*)d_ws, Xu, wup, cuv, B);

  int nblk = (total + 63) / 64;
  if (ws_size >= need){
    short* interg = (short*)(wsb + inter_off);
    float* pgg    = (float*)(wsb + inter_off + (size_t)total*64*2);
    ncf_gather<<<2048, 256, 0, stream>>>(item, Wi_mlp, Wi_gmf, wup, cuv,
                                         interg, pgg, N, total);
    ncf_dense<<<nblk, 256, 0, stream>>>(interg, pgg,
        W1iT, W2T, W3T, b2, b3, Wp, bp, Xu,
        (float*)d_out, N, total, B);
  } else {
    ncf_main_fused<<<nblk, 256, 0, stream>>>(item, Wi_mlp, Wi_gmf,
        W1iT, W2T, W3T, b2, b3, Wp, bp, Xu, wup, cuv,
        (float*)d_out, N, total, B);
  }
}

// Round 8
// 71.692 us; speedup vs baseline: 1.8672x; 1.5120x over previous
//
#include <hip/hip_runtime.h>

// NCF fused forward, v8: operand-swapped GEMMs (D[col][pair]) + fp8 MLP tower.
//  ncf_prep_w : W1uT bf16 [128][64]; W1iT/W2T/W3T fp8 [out][in]; c1 = b1 + bi_mlp@W1i
//  ncf_prep_u : 64 users/block MFMA: Xu[b] = (eu_m+bu_m)@W1u + c1 (f32);
//               wup[b] = (eu_g+bu_g).*Wp[0:64]; cu[b] = wup[b].bi_gmf
//  ncf_main   : 64 pairs/block, 256 thr. store(item rows->fp8 LDS, pg dot) | bar |
//               G1 fp8 K=64 (+Xu, packed b32 writes) | bar | G2 fp8 K=128 | bar |
//               G3 fp8 K=64 -> in-register final dot + sigmoid -> out. 3 barriers.

typedef __attribute__((ext_vector_type(8))) short bf16x8;
typedef __attribute__((ext_vector_type(4))) float f32x4;

__device__ __forceinline__ short f2bf(float x){
  unsigned u = __float_as_uint(x);
  u += 0x7fffu + ((u >> 16) & 1u);
  return (short)(u >> 16);
}
__device__ __forceinline__ unsigned char f2fp8(float x){
  return (unsigned char)(__builtin_amdgcn_cvt_pk_fp8_f32(x, 0.f, 0, false) & 0xFF);
}

// ws layout (bytes):
//   0      W1uT bf16 [128][64]  (16384)
//   16384  W1iT fp8  [128][64]  (8192)
//   24576  W2T  fp8  [64][128]  (8192)
//   32768  W3T  fp8  [32][64]   (2048)
//   34816  c1   f32  [128]      (512)
//   36864  Xu   f32  [B][128];  then wup f32 [B][64];  cu f32 [B]

__global__ __launch_bounds__(256) void ncf_prep_w(
    const float* __restrict__ W1, const float* __restrict__ W2,
    const float* __restrict__ W3, const float* __restrict__ b1,
    const float* __restrict__ bi_mlp, char* __restrict__ ws)
{
  if (blockIdx.x == 104){
    int j = threadIdx.x;
    if (j < 128){
      float acc = b1[j];
      #pragma unroll 4
      for (int k = 0; k < 64; k++)
        acc += bi_mlp[k] * W1[(64 + k)*128 + j];
      ((float*)(ws + 34816))[j] = acc;
    }
    return;
  }
  int i = blockIdx.x * 256 + threadIdx.x;
  if (i < 8192){                                 // W1uT bf16 [col][k] = W1[k][col]
    int col = i >> 6, k = i & 63;
    ((short*)ws)[i] = f2bf(W1[k*128 + col]);
  } else if (i < 16384){                         // W1iT fp8 [col][k] = W1[64+k][col]
    int t = i - 8192; int col = t >> 6, k = t & 63;
    ((unsigned char*)(ws + 16384))[t] = f2fp8(W1[(64 + k)*128 + col]);
  } else if (i < 24576){                         // W2T fp8 [col][k] = W2[k][col]
    int t = i - 16384; int col = t >> 7, k = t & 127;
    ((unsigned char*)(ws + 24576))[t] = f2fp8(W2[k*64 + col]);
  } else {                                       // W3T fp8 [col][k] = W3[k][col]
    int t = i - 24576; int col = t >> 6, k = t & 63;
    ((unsigned char*)(ws + 32768))[t] = f2fp8(W3[k*32 + col]);
  }
}

// ---- prep_u: 64 users per block, bf16 MFMA GEMM K=64 (r4-proven) ----
__global__ __launch_bounds__(256) void ncf_prep_u(
    const int* __restrict__ user,
    const float* __restrict__ Wu_gmf, const float* __restrict__ bu_gmf,
    const float* __restrict__ Wu_mlp, const float* __restrict__ bu_mlp,
    const float* __restrict__ bi_gmf, const float* __restrict__ Wp,
    const short* __restrict__ W1uT, const float* __restrict__ c1,
    float* __restrict__ Xu, float* __restrict__ wup, float* __restrict__ cu)
{
  __shared__ __align__(16) short s_eu[64][72];
  const int tid = threadIdx.x;
  const int r = tid >> 2, q = tid & 3;
  const int b = blockIdx.x * 64 + r;
  long u = (long)user[b];
  {
    const float4* ump = (const float4*)(Wu_mlp + u*64) + q*4;
    const float4* bmp = (const float4*)(bu_mlp) + q*4;
    const float4* ugp = (const float4*)(Wu_gmf + u*64) + q*4;
    const float4* bgp = (const float4*)(bu_gmf) + q*4;
    const float4* wpp = (const float4*)(Wp) + q*4;
    const float4* bip = (const float4*)(bi_gmf) + q*4;
    float4* wdst = (float4*)(wup + (long)b*64) + q*4;
    bf16x8 ea[2];
    float cacc = 0.f;
    #pragma unroll
    for (int j = 0; j < 4; j++){
      float4 m = ump[j], mb = bmp[j];
      int h = j >> 1, s = (j & 1) * 4;
      ea[h][s+0] = f2bf(m.x + mb.x); ea[h][s+1] = f2bf(m.y + mb.y);
      ea[h][s+2] = f2bf(m.z + mb.z); ea[h][s+3] = f2bf(m.w + mb.w);
      float4 g = ugp[j], gb = bgp[j], wp = wpp[j], bi = bip[j];
      float4 wg; wg.x = (g.x+gb.x)*wp.x; wg.y = (g.y+gb.y)*wp.y;
                 wg.z = (g.z+gb.z)*wp.z; wg.w = (g.w+gb.w)*wp.w;
      wdst[j] = wg;
      cacc += wg.x*bi.x + wg.y*bi.y + wg.z*bi.z + wg.w*bi.w;
    }
    *(bf16x8*)&s_eu[r][q*16]     = ea[0];
    *(bf16x8*)&s_eu[r][q*16 + 8] = ea[1];
    cacc += __shfl_xor(cacc, 1);
    cacc += __shfl_xor(cacc, 2);
    if (q == 0) cu[b] = cacc;
  }
  __syncthreads();

  const int w = tid >> 6, l = tid & 63, lr = l & 15, lg = l >> 4;
  f32x4 acc[4][2];
  #pragma unroll
  for (int mt = 0; mt < 4; mt++)
    #pragma unroll
    for (int nt = 0; nt < 2; nt++)
      acc[mt][nt] = (f32x4){0.f, 0.f, 0.f, 0.f};
  #pragma unroll
  for (int ks = 0; ks < 2; ks++){
    bf16x8 af[4];
    #pragma unroll
    for (int mt = 0; mt < 4; mt++)
      af[mt] = *(const bf16x8*)&s_eu[mt*16 + lr][ks*32 + lg*8];
    #pragma unroll
    for (int nt = 0; nt < 2; nt++){
      bf16x8 bf_ = *(const bf16x8*)&W1uT[(w*32 + nt*16 + lr)*64 + ks*32 + lg*8];
      #pragma unroll
      for (int mt = 0; mt < 4; mt++)
        acc[mt][nt] = __builtin_amdgcn_mfma_f32_16x16x32_bf16(af[mt], bf_, acc[mt][nt], 0, 0, 0);
    }
  }
  #pragma unroll
  for (int nt = 0; nt < 2; nt++){
    int col = w*32 + nt*16 + lr;
    float cc = c1[col];
    #pragma unroll
    for (int mt = 0; mt < 4; mt++)
      #pragma unroll
      for (int rr = 0; rr < 4; rr++){
        int row = mt*16 + lg*4 + rr;
        Xu[(long)(blockIdx.x*64 + row)*128 + col] = acc[mt][nt][rr] + cc;
      }
  }
}

// ---- main ----
__global__ __launch_bounds__(256) void ncf_main(
    const int* __restrict__ item,
    const float* __restrict__ Wi_mlp, const float* __restrict__ Wi_gmf,
    const unsigned char* __restrict__ W1iT, const unsigned char* __restrict__ W2T,
    const unsigned char* __restrict__ W3T,
    const float* __restrict__ b2, const float* __restrict__ b3,
    const float* __restrict__ Wp, const float* __restrict__ bp,
    const float* __restrict__ Xu, const float* __restrict__ wup,
    const float* __restrict__ cu,
    float* __restrict__ out, int N, int total, int Bsz)
{
  __shared__ __align__(16) unsigned char s_item[64][80];  // item mlp rows, fp8
  __shared__ __align__(16) unsigned char s_h1[64][136];   // h1 fp8
  __shared__ __align__(16) unsigned char s_h2[64][80];    // h2 fp8
  __shared__ __align__(16) float s_xu[2][128];
  __shared__            float s_pg[64];

  const int tid = threadIdx.x;
  const int p0  = blockIdx.x * 64;
  const int b0  = p0 / N;
  const int thr = (b0 + 1) * N;
  const int r   = tid >> 2, q = tid & 3;
  const int w   = tid >> 6, l = tid & 63;
  const int lr  = l & 15,  lg = l >> 4;
  const float bp0 = bp[0];

  // ---- store: item mlp row -> fp8 LDS; pg dot; Xu -> LDS ----
  {
    int p = p0 + r;
    int b = b0 + ((p >= thr) ? 1 : 0);
    long ib = (long)item[p] * 64;
    const float4* mp = (const float4*)(Wi_mlp + ib) + q*4;
    const float4* gp = (const float4*)(Wi_gmf + ib) + q*4;
    const float4* wq = (const float4*)(wup + (long)b*64) + q*4;
    float pg = 0.f;
    int pk[4];
    #pragma unroll
    for (int j = 0; j < 4; j++){
      float4 m = mp[j], g = gp[j], wv = wq[j];
      pg += g.x*wv.x + g.y*wv.y + g.z*wv.z + g.w*wv.w;
      int t_ = __builtin_amdgcn_cvt_pk_fp8_f32(m.x, m.y, 0, false);
      t_     = __builtin_amdgcn_cvt_pk_fp8_f32(m.z, m.w, t_, true);
      pk[j] = t_;
    }
    *(int4*)&s_item[r][q*16] = (int4){pk[0], pk[1], pk[2], pk[3]};
    pg += __shfl_xor(pg, 1);
    pg += __shfl_xor(pg, 2);
    if (q == 0) s_pg[r] = pg + cu[b];
    int i2 = tid >> 7, col = tid & 127;
    int bb = b0 + i2; if (bb >= Bsz) bb = Bsz - 1;
    s_xu[i2][col] = Xu[(long)bb*128 + col];
  }
  __syncthreads();

  // ---- G1: D[col128][pair64] = W1iT(fp8) x item(fp8), K=64; +Xu, relu -> s_h1 ----
  {
    f32x4 acc[2][4];   // [mt][nt]
    #pragma unroll
    for (int mt = 0; mt < 2; mt++)
      #pragma unroll
      for (int nt = 0; nt < 4; nt++)
        acc[mt][nt] = (f32x4){0.f, 0.f, 0.f, 0.f};
    #pragma unroll
    for (int ks = 0; ks < 2; ks++){
      long bfrag[4];
      #pragma unroll
      for (int nt = 0; nt < 4; nt++)
        bfrag[nt] = *(const long*)&s_item[nt*16 + lr][ks*32 + lg*8];
      #pragma unroll
      for (int mt = 0; mt < 2; mt++){
        long af = *(const long*)&W1iT[((w*2 + mt)*16 + lr)*64 + ks*32 + lg*8];
        #pragma unroll
        for (int nt = 0; nt < 4; nt++)
          acc[mt][nt] = __builtin_amdgcn_mfma_f32_16x16x32_fp8_fp8(af, bfrag[nt], acc[mt][nt], 0, 0, 0);
      }
    }
    #pragma unroll
    for (int mt = 0; mt < 2; mt++){
      int colb = (w*2 + mt)*16 + lg*4;
      #pragma unroll
      for (int nt = 0; nt < 4; nt++){
        int pair = nt*16 + lr;
        int bl = (p0 + pair >= thr) ? 1 : 0;
        float4 xv = *(const float4*)&s_xu[bl][colb];
        float v0 = acc[mt][nt][0] + xv.x; v0 = v0 > 0.f ? v0 : 0.f;
        float v1 = acc[mt][nt][1] + xv.y; v1 = v1 > 0.f ? v1 : 0.f;
        float v2 = acc[mt][nt][2] + xv.z; v2 = v2 > 0.f ? v2 : 0.f;
        float v3 = acc[mt][nt][3] + xv.w; v3 = v3 > 0.f ? v3 : 0.f;
        int t_ = __builtin_amdgcn_cvt_pk_fp8_f32(v0, v1, 0, false);
        t_     = __builtin_amdgcn_cvt_pk_fp8_f32(v2, v3, t_, true);
        *(int*)&s_h1[pair][colb] = t_;
      }
    }
  }
  __syncthreads();

  // ---- G2: D[col64][pair64] = W2T(fp8) x h1(fp8), K=128; +b2, relu -> s_h2 ----
  {
    f32x4 acc[4];   // [nt]
    #pragma unroll
    for (int nt = 0; nt < 4; nt++) acc[nt] = (f32x4){0.f, 0.f, 0.f, 0.f};
    #pragma unroll
    for (int ks = 0; ks < 4; ks++){
      long af = *(const long*)&W2T[(w*16 + lr)*128 + ks*32 + lg*8];
      #pragma unroll
      for (int nt = 0; nt < 4; nt++){
        long bf_ = *(const long*)&s_h1[nt*16 + lr][ks*32 + lg*8];
        acc[nt] = __builtin_amdgcn_mfma_f32_16x16x32_fp8_fp8(af, bf_, acc[nt], 0, 0, 0);
      }
    }
    int colb = w*16 + lg*4;
    float4 b2v = *(const float4*)&b2[colb];
    #pragma unroll
    for (int nt = 0; nt < 4; nt++){
      int pair = nt*16 + lr;
      float v0 = acc[nt][0] + b2v.x; v0 = v0 > 0.f ? v0 : 0.f;
      float v1 = acc[nt][1] + b2v.y; v1 = v1 > 0.f ? v1 : 0.f;
      float v2 = acc[nt][2] + b2v.z; v2 = v2 > 0.f ? v2 : 0.f;
      float v3 = acc[nt][3] + b2v.w; v3 = v3 > 0.f ? v3 : 0.f;
      int t_ = __builtin_amdgcn_cvt_pk_fp8_f32(v0, v1, 0, false);
      t_     = __builtin_amdgcn_cvt_pk_fp8_f32(v2, v3, t_, true);
      *(int*)&s_h2[pair][colb] = t_;
    }
  }
  __syncthreads();

  // ---- G3: D[col32][pair16/wave] = W3T(fp8) x h2(fp8), K=64; final dot + sigmoid ----
  {
    f32x4 acc[2];   // [mt]
    #pragma unroll
    for (int mt = 0; mt < 2; mt++) acc[mt] = (f32x4){0.f, 0.f, 0.f, 0.f};
    #pragma unroll
    for (int ks = 0; ks < 2; ks++){
      long bf_ = *(const long*)&s_h2[w*16 + lr][ks*32 + lg*8];
      #pragma unroll
      for (int mt = 0; mt < 2; mt++){
        long af = *(const long*)&W3T[(mt*16 + lr)*64 + ks*32 + lg*8];
        acc[mt] = __builtin_amdgcn_mfma_f32_16x16x32_fp8_fp8(af, bf_, acc[mt], 0, 0, 0);
      }
    }
    float t = 0.f;
    #pragma unroll
    for (int mt = 0; mt < 2; mt++){
      int colb = mt*16 + lg*4;
      float4 b3v = *(const float4*)&b3[colb];
      float4 wpv = *(const float4*)&Wp[64 + colb];
      float v0 = acc[mt][0] + b3v.x; v0 = v0 > 0.f ? v0 : 0.f;
      float v1 = acc[mt][1] + b3v.y; v1 = v1 > 0.f ? v1 : 0.f;
      float v2 = acc[mt][2] + b3v.z; v2 = v2 > 0.f ? v2 : 0.f;
      float v3 = acc[mt][3] + b3v.w; v3 = v3 > 0.f ? v3 : 0.f;
      t += v0*wpv.x + v1*wpv.y + v2*wpv.z + v3*wpv.w;
    }
    t += __shfl_xor(t, 16);
    t += __shfl_xor(t, 32);
    if (l < 16){
      int pair = w*16 + l;
      int p = p0 + pair;
      if (p < total){
        float z = t + s_pg[pair] + bp0;
        out[p] = 1.f / (1.f + __expf(-z));
      }
    }
  }
}

extern "C" void kernel_launch(void* const* d_in, const int* in_sizes, int n_in,
                              void* d_out, int out_size, void* d_ws, size_t ws_size,
                              hipStream_t stream)
{
  const int*   user   = (const int*)  d_in[0];
  const int*   item   = (const int*)  d_in[1];
  const float* Wu_gmf = (const float*)d_in[3];
  const float* bu_gmf = (const float*)d_in[4];
  const float* Wu_mlp = (const float*)d_in[5];
  const float* bu_mlp = (const float*)d_in[6];
  const float* Wi_gmf = (const float*)d_in[7];
  const float* bi_gmf = (const float*)d_in[8];
  const float* Wi_mlp = (const float*)d_in[9];
  const float* bi_mlp = (const float*)d_in[10];
  const float* W1     = (const float*)d_in[11];
  const float* b1     = (const float*)d_in[12];
  const float* W2     = (const float*)d_in[13];
  const float* b2     = (const float*)d_in[14];
  const float* W3     = (const float*)d_in[15];
  const float* b3     = (const float*)d_in[16];
  const float* Wp     = (const float*)d_in[17];
  const float* bp     = (const float*)d_in[18];

  int B     = in_sizes[0];            // 4096
  int total = in_sizes[1];            // 409600
  int N     = total / B;              // 100

  char* wsb = (char*)d_ws;
  short*         W1uT = (short*)wsb;
  unsigned char* W1iT = (unsigned char*)(wsb + 16384);
  unsigned char* W2T  = (unsigned char*)(wsb + 24576);
  unsigned char* W3T  = (unsigned char*)(wsb + 32768);
  float*         c1   = (float*)(wsb + 34816);
  float*         Xu   = (float*)(wsb + 36864);
  float*         wup  = Xu  + (size_t)B * 128;
  float*         cuv  = wup + (size_t)B * 64;

  ncf_prep_w<<<105, 256, 0, stream>>>(W1, W2, W3, b1, bi_mlp, wsb);
  ncf_prep_u<<<B/64, 256, 0, stream>>>(user, Wu_gmf, bu_gmf, Wu_mlp, bu_mlp,
                                       bi_gmf, Wp, W1uT, c1, Xu, wup, cuv);

  int nblk = (total + 63) / 64;       // 6400
  ncf_main<<<nblk, 256, 0, stream>>>(item, Wi_mlp, Wi_gmf,
      W1iT, W2T, W3T, b2, b3, Wp, bp, Xu, wup, cuv,
      (float*)d_out, N, total, B);
}